// Round 1
// baseline (571.961 us; speedup 1.0000x reference)
//
#include <hip/hip_runtime.h>
#include <math.h>

// EMRouting: B=8,H=12,W=12,K=3,CIN=16,COUT=32,P=16 -> 1152 positions x 144 votes
#define NPOS 1152
#define NN   144
#define COUT 32
#define PP   16
#define EPSF 1e-7f
#define LOG2PI 1.8378770664093453f

#define MU_OFF   0
#define A_OFF    589824            // 1152*32*16
#define SIG_OFF  626688            // + 1152*32

// Block = 256 threads = 4 waves. Lane layout: cout = tid&31, slot = tid>>5 (8 n-slots,
// each handles n = slot + 8*j, j=0..17). Softmax over cout = 32-lane shuffle (masks 1..16),
// n_sub pair-reduce = shuffle xor 32. All within-wave, no barrier in the n-loop.
__global__ void __launch_bounds__(256)
em_routing_kernel(const float* __restrict__ V,
                  const float* __restrict__ a,
                  const float* __restrict__ Bu,
                  const float* __restrict__ Ba,
                  const float* __restrict__ Rin,
                  float* __restrict__ out)
{
    const int pos  = blockIdx.x;
    const int tid  = threadIdx.x;
    const int c    = tid & 31;   // cout lane
    const int slot = tid >> 5;   // 0..7
    const int wave = tid >> 6;   // 0..3

    const float* Vp = V + (size_t)pos * (NN * COUT * PP);
    const float* Rp = Rin + (size_t)pos * (NN * COUT);

    __shared__ float a_s[NN];
    __shared__ float red[4][COUT][33];   // per-wave partials: [0]=S0, [1..16]=S1, [17..32]=S2
    __shared__ float fin[COUT][33];
    __shared__ float mu_s[COUT][17];     // +1 pad vs 16 (bank spread)
    __shared__ float wp_s[COUT][17];     // 1/(2*sigma^2+EPS)
    __shared__ float sg_s[COUT][17];
    __shared__ float cl_s[COUT];         // log(a_out) + log_p1
    __shared__ float xs[COUT];
    __shared__ float sl_s[COUT];         // sum_p log(sigma^2)
    __shared__ float ao_s[COUT];
    __shared__ float nrm_s;

    for (int i = tid; i < NN; i += 256) a_s[i] = a[pos * NN + i];
    __syncthreads();

    const float lam_tab[3] = {0.01f * (1.f - 0.95f),
                              0.01f * (1.f - 0.95f * 0.95f),
                              0.01f * (1.f - 0.95f * 0.95f * 0.95f)};

    float mu_r[PP], wp_r[PP];
    float cl_r = 0.f;

    for (int it = 0; it < 3; ++it) {
        if (it > 0) {
            #pragma unroll
            for (int p = 0; p < PP; ++p) {
                mu_r[p] = mu_s[c][p];
                wp_r[p] = wp_s[c][p];
            }
            cl_r = cl_s[c];
        }

        float S0 = 0.f, S1[PP], S2[PP];
        #pragma unroll
        for (int p = 0; p < PP; ++p) { S1[p] = 0.f; S2[p] = 0.f; }

        for (int j = 0; j < 18; ++j) {
            const int n = slot + (j << 3);
            const float4* vp = (const float4*)(Vp + (size_t)n * (COUT * PP) + c * PP);
            float4 q0 = vp[0], q1 = vp[1], q2 = vp[2], q3 = vp[3];
            float v[PP] = {q0.x,q0.y,q0.z,q0.w, q1.x,q1.y,q1.z,q1.w,
                           q2.x,q2.y,q2.z,q2.w, q3.x,q3.y,q3.z,q3.w};
            float Rw;
            if (it == 0) {
                Rw = Rp[n * COUT + c] * a_s[n];     // initial R from input
            } else {
                // E-step: logit = log(a_out)+log_p1 - sum_p (v-mu)^2 * wp
                float acc = 0.f;
                #pragma unroll
                for (int p = 0; p < PP; ++p) {
                    float d = v[p] - mu_r[p];
                    acc = fmaf(d * wp_r[p], d, acc);
                }
                float logit = cl_r - acc;
                float m = logit;
                #pragma unroll
                for (int msk = 1; msk <= 16; msk <<= 1)
                    m = fmaxf(m, __shfl_xor(m, msk, 64));
                float e = __expf(logit - m);
                float sum = e;
                #pragma unroll
                for (int msk = 1; msk <= 16; msk <<= 1)
                    sum += __shfl_xor(sum, msk, 64);
                Rw = (e / sum) * a_s[n];
            }
            // M-step accumulation
            S0 += Rw;
            #pragma unroll
            for (int p = 0; p < PP; ++p) {
                float t = Rw * v[p];
                S1[p] += t;
                S2[p] = fmaf(t, v[p], S2[p]);
            }
        }

        // fold n_sub pairs within the wave
        S0 += __shfl_xor(S0, 32, 64);
        #pragma unroll
        for (int p = 0; p < PP; ++p) {
            S1[p] += __shfl_xor(S1[p], 32, 64);
            S2[p] += __shfl_xor(S2[p], 32, 64);
        }
        if ((tid & 32) == 0) {
            red[wave][c][0] = S0;
            #pragma unroll
            for (int p = 0; p < PP; ++p) {
                red[wave][c][1 + p]  = S1[p];
                red[wave][c][17 + p] = S2[p];
            }
        }
        __syncthreads();
        for (int idx = tid; idx < COUT * 33; idx += 256) {
            int cc = idx / 33, k = idx - cc * 33;
            fin[cc][k] = red[0][cc][k] + red[1][cc][k] + red[2][cc][k] + red[3][cc][k];
        }
        __syncthreads();

        // finalize per cout (32 threads; tiny vs the 144-n loop)
        if (tid < COUT) {
            const int cc = tid;
            float d0  = fin[cc][0];
            float inv = 1.f / (d0 + EPSF);
            float sumlog = 0.f;
            #pragma unroll
            for (int p = 0; p < PP; ++p) {
                float s1 = fin[cc][1 + p];
                float s2 = fin[cc][17 + p];
                float mu = s1 * inv;
                float sg = (s2 - 2.f * mu * s1 + mu * mu * d0) * inv;
                sg = fmaxf(sg, 1e-30f);            // guard cancellation -> log NaN
                mu_s[cc][p] = mu;
                sg_s[cc][p] = sg;
                wp_s[cc][p] = 1.f / (2.f * sg + EPSF);
                sumlog += logf(sg);
            }
            sl_s[cc] = sumlog;
            // sum_p cost_h = d0*(P*Beta_u + 0.5*sumlog); x = Lam*(Beta_a - that)
            xs[cc] = lam_tab[it] * (Ba[cc] - d0 * (16.f * Bu[cc] + 0.5f * sumlog));
        }
        __syncthreads();
        if (tid == 0) {
            float nn2 = 0.f;
            for (int cc = 0; cc < COUT; ++cc) nn2 += xs[cc] * xs[cc];
            nrm_s = sqrtf(nn2);
        }
        __syncthreads();
        if (tid < COUT) {
            const int cc = tid;
            float y  = xs[cc] / fmaxf(nrm_s, 1e-12f);
            float ao = 1.f / (1.f + expf(-y));
            ao_s[cc] = ao;
            // log_p1 = -0.5*(P*log(2pi) + sum_p log sigma^2) + EPS
            cl_s[cc] = logf(ao) + (-0.5f * (16.f * LOG2PI + sl_s[cc]) + EPSF);
        }
        __syncthreads();
    }

    // outputs from iteration 2's M-step
    for (int idx = tid; idx < COUT * PP; idx += 256) {
        int cc = idx >> 4, p = idx & 15;
        out[MU_OFF  + (size_t)pos * (COUT * PP) + idx] = mu_s[cc][p];
        out[SIG_OFF + (size_t)pos * (COUT * PP) + idx] = sg_s[cc][p];
    }
    if (tid < COUT) out[A_OFF + pos * COUT + tid] = ao_s[tid];
}

extern "C" void kernel_launch(void* const* d_in, const int* in_sizes, int n_in,
                              void* d_out, int out_size, void* d_ws, size_t ws_size,
                              hipStream_t stream) {
    const float* V  = (const float*)d_in[0];
    const float* a  = (const float*)d_in[1];
    const float* Bu = (const float*)d_in[2];
    const float* Ba = (const float*)d_in[3];
    const float* R  = (const float*)d_in[4];
    float* out = (float*)d_out;
    em_routing_kernel<<<NPOS, 256, 0, stream>>>(V, a, Bu, Ba, R, out);
}